// Round 10
// baseline (1798.978 us; speedup 1.0000x reference)
//
#include <hip/hip_runtime.h>
#include <hip/hip_bf16.h>
#include <hip/hip_fp16.h>
#include <stdint.h>

// Seq2Seq LSTM: B=4096, H=512, E=128, 32 enc + 32 dec steps, V_tgt=128.
// Round 20: BM=256 TILES + DBUF COUNTED-VMCNT K-LOOP.
// Ledger: R13 sched micro-opt null (at 4 blk/CU); R11/12/14 manual-sync
// much worse; R16 LDS-free much worse; R15/R17 work-reduction, R18
// fat-tiles won; R19 outproj-fusion null (reverted).
// Model: per-step wall = launch (~5us) + L3-BW-bound staging. Kernel
// boundaries invalidate L2 (cross-XCD correctness), so each step pulls
// A*(#c-blocks)+B*(#m-blocks) through L3: R18 = 128 MB/step. This round:
// 256m x 128n-eff tiles -> 96 MB/step (-25%). Grid 256 x 512thr = 1
// block/CU; no co-resident-block overlap left, so the K-loop is double-
// buffered (A+B, 96 KB LDS) with counted s_waitcnt vmcnt(6) + raw
// s_barrier (R13-proven pattern) + setprio around MFMA.
// Wave = 64m x (4 gates x 16 hcols): 4 m-frags x 4 gate-frags; the
// all-4-gates-per-lane fused epilogue is preserved (mf loop 2->4).
// maxlen now per-256-row tile. Same per-lane operands + accumulation
// order -> absmax unchanged.

#define NB     4096
#define SSRC   32
#define STGT   32
#define NVSRC  96
#define NVTGT  128
#define ED     128
#define HD     512
#define G4     2048   // 4*HD
#define NBHD   ((size_t)NB * HD)

typedef __attribute__((ext_vector_type(8))) _Float16 half8;
typedef __attribute__((ext_vector_type(4))) float fx4;

#define AS_G __attribute__((address_space(1)))
#define AS_L __attribute__((address_space(3)))

__device__ __forceinline__ void gl2lds16(const void* g, void* l) {
    // async global->LDS DMA, 16B/lane; LDS dest = wave-uniform base + lane*16
    __builtin_amdgcn_global_load_lds((const AS_G uint32_t*)g, (AS_L uint32_t*)l, 16, 0, 0);
}

__device__ __forceinline__ float sigf(float x) { return 1.0f / (1.0f + __expf(-x)); }
__device__ __forceinline__ float tanhfast(float x) { return 1.0f - 2.0f / (__expf(2.0f * x) + 1.0f); }

// One launch converts eWhh, dWhh, Wout to fp16 (three segments).
__global__ __launch_bounds__(256) void convert_all(
    const float* __restrict__ s1, int n1, _Float16* __restrict__ d1,
    const float* __restrict__ s2, int n2, _Float16* __restrict__ d2,
    const float* __restrict__ s3, int n3, _Float16* __restrict__ d3)
{
    int i = (int)blockIdx.x * 256 + threadIdx.x;
    if (i < n1) { d1[i] = (_Float16)s1[i]; return; }
    i -= n1;
    if (i < n2) { d2[i] = (_Float16)s2[i]; return; }
    i -= n2;
    if (i < n3) d3[i] = (_Float16)s3[i];
}

// Both Wih transposes (eWih, dWih) in one launch. R=G4, C=ED.
__global__ __launch_bounds__(256) void transpose2_f32(
    const float* __restrict__ inA, float* __restrict__ outTA,
    const float* __restrict__ inB, float* __restrict__ outTB)
{
    __shared__ float ls[32][33];
    int bid = (int)blockIdx.x;
    const float* in; float* outT;
    if (bid < 256) { in = inA; outT = outTA; }
    else           { in = inB; outT = outTB; bid -= 256; }
    const int rtiles = G4 / 32;                  // 64
    const int bx = bid % rtiles;                 // r-tile
    const int by = bid / rtiles;                 // c-tile
    const int tx = threadIdx.x & 31, ty = threadIdx.x >> 5;   // ty 0..7
    #pragma unroll
    for (int i = 0; i < 4; i++) {
        int rr = ty + i * 8;
        ls[rr][tx] = in[(size_t)(bx * 32 + rr) * ED + by * 32 + tx];
    }
    __syncthreads();
    #pragma unroll
    for (int i = 0; i < 4; i++) {
        int rr = ty + i * 8;
        outT[(size_t)(by * 32 + rr) * G4 + bx * 32 + tx] = ls[tx][rr];
    }
}

// proj[v][hcol][gate] = emb[v,:]·Wih[g,:] + bih[g] + bhh[g]  (gate-contig).
// Both vocab tables in one launch: blocks [0,96) = src, [96,224) = tgt.
__global__ __launch_bounds__(256) void build_tables2(
    const float* __restrict__ embS, const float* __restrict__ WTS,
    const float* __restrict__ bihS, const float* __restrict__ bhhS,
    float* __restrict__ projS,
    const float* __restrict__ embT, const float* __restrict__ WTT,
    const float* __restrict__ bihT, const float* __restrict__ bhhT,
    float* __restrict__ projT)
{
    __shared__ float embL[8][ED];
    int bid = (int)blockIdx.x;
    const float *emb, *WT, *bih, *bhh; float* proj;
    if (bid < (NVSRC / 8) * 8) { emb = embS; WT = WTS; bih = bihS; bhh = bhhS; proj = projS; }
    else { bid -= (NVSRC / 8) * 8; emb = embT; WT = WTT; bih = bihT; bhh = bhhT; proj = projT; }
    const int gc = bid & 7;
    const int vc = bid >> 3;
    const int g  = gc * 256 + threadIdx.x;
    for (int i = threadIdx.x; i < 8 * ED; i += 256)
        embL[i >> 7][i & (ED - 1)] = emb[(size_t)(vc * 8 + (i >> 7)) * ED + (i & (ED - 1))];
    __syncthreads();
    float acc[8] = {0, 0, 0, 0, 0, 0, 0, 0};
    for (int e = 0; e < ED; e++) {
        float w = WT[(size_t)e * G4 + g];
        #pragma unroll
        for (int v = 0; v < 8; v++) acc[v] += embL[v][e] * w;
    }
    float bb = bih[g] + bhh[g];
    const int gate = g >> 9, hcol = g & (HD - 1);
    #pragma unroll
    for (int v = 0; v < 8; v++)
        proj[(((size_t)(vc * 8 + v) * HD + hcol) << 2) + gate] = acc[v] + bb;
}

// Counting sort of rows by src length (keys 1..32). Single block.
// maxlen is per 256-row tile (16 tiles) to match BM=256 lstm_step.
__global__ __launch_bounds__(256) void sort_rows(
    const int* __restrict__ lens, int* __restrict__ perm,
    int* __restrict__ lens_s, int* __restrict__ maxlen)
{
    __shared__ int hist[33];
    __shared__ int base[33];
    const int tid = threadIdx.x;
    if (tid < 33) hist[tid] = 0;
    __syncthreads();
    for (int i = tid; i < NB; i += 256) atomicAdd(&hist[lens[i]], 1);
    __syncthreads();
    if (tid == 0) {
        int s = 0;
        for (int l = 1; l <= 32; l++) { base[l] = s; s += hist[l]; }
    }
    __syncthreads();
    for (int i = tid; i < NB; i += 256) {
        int l = lens[i];
        int pos = atomicAdd(&base[l], 1);
        perm[pos] = i;
        lens_s[pos] = l;
    }
    __syncthreads();
    if (tid < 16) maxlen[tid] = lens_s[tid * 256 + 255];
}

// Gathers both src and tgt sequences through perm in one launch.
__global__ __launch_bounds__(256) void gather_seq2(
    const int* __restrict__ src, const int* __restrict__ tgt,
    const int* __restrict__ perm,
    int* __restrict__ src_s, int* __restrict__ tgt_s)
{
    int i = (int)blockIdx.x * 256 + threadIdx.x;   // over 2*NB*32
    int half = i >> 17;                            // NB*32 = 131072 = 1<<17
    int k = i & ((NB * 32) - 1);
    int row = k >> 5, t = k & 31;
    if (half == 0) src_s[k] = src[perm[row] * 32 + t];
    else           tgt_s[k] = tgt[perm[row] * 32 + t];
}

// Gate GEMM, 256m x 128n (4 gates x 32 hcols) per block + fused epilogue.
// 256 blocks x 512 threads (8 waves) = 1 block/CU. Wave = 64m x 64n:
// 4 m-frags x 4 n-frags (n-frag == gate at hgrp). K-loop: A+B double-
// buffered (96 KB LDS), counted vmcnt(6) + raw s_barrier: the next
// tile's 6 loads stay in flight across both barriers.
__global__ __launch_bounds__(512, 2) void lstm_step(
    const _Float16* __restrict__ h_r, _Float16* __restrict__ h_w,
    float* __restrict__ c_state,
    const float* __restrict__ proj,      // [tok][hcol][4]
    const int* __restrict__ seq_s, const int* __restrict__ lens_s,
    const int* __restrict__ maxlen,
    const _Float16* __restrict__ W,
    _Float16* __restrict__ hfinal,
    int t, int is_enc, int skip_gemm)
{
    __shared__ __align__(16) _Float16 lsA[2][256 * 64];   // 64 KB
    __shared__ __align__(16) _Float16 lsB[2][128 * 64];   // 32 KB

    const int tid = threadIdx.x;
    const int lane = tid & 63;
    const int wid  = tid >> 6;                     // 0..7
    const int srow = lane >> 3;                    // staging row-in-group
    const int skc  = (((lane & 7) ^ srow)) << 3;   // XOR-swizzled k-chunk
    const int wm   = (wid & 3) * 64;               // wave m-offset (0..192)
    const int hgrp = (wid >> 2) * 16;              // hcol 16-group in c-tile
    const int quad = lane >> 4;
    const int l15  = lane & 15;

    // XCD mapping: per-XCD ws = 8 m-tiles x 4 c-tiles (bijective over 16x16)
    const int x = (int)blockIdx.x & 7, j = (int)blockIdx.x >> 3;   // j 0..31
    const int mt = (x & 1) * 8 + (j & 7);              // m-tile 0..15 (sorted)
    const int m0 = mt * 256;
    const int ct = (x >> 1) * 4 + (j >> 3);            // c-tile 0..15
    const int c0 = ct * 32;

    // whole tile frozen: every row already wrote hfinal; c_state holds finals
    if (is_enc && t >= maxlen[mt]) return;

    const _Float16 *ag[4], *bg[2];
    #pragma unroll
    for (int i = 0; i < 4; i++) {
        int lr = wid * 32 + i * 8 + srow;              // local A row 0..255
        ag[i] = h_r + (size_t)(m0 + lr) * HD + skc;
    }
    #pragma unroll
    for (int i = 0; i < 2; i++) {
        int lr = wid * 16 + i * 8 + srow;              // local B row 0..127
        int wr = (lr >> 5) * HD + c0 + (lr & 31);      // gate=lr>>5, hc=lr&31
        bg[i] = W + (size_t)wr * HD + skc;
    }

    fx4 acc[4][4];
    #pragma unroll
    for (int i = 0; i < 4; i++)
        #pragma unroll
        for (int jj = 0; jj < 4; jj++)
            acc[i][jj] = fx4{0.f, 0.f, 0.f, 0.f};

    if (!skip_gemm) {
        // prologue: tile0 -> buf0, tile1 -> buf1 (6 loads/thread each)
        #pragma unroll
        for (int i = 0; i < 4; i++)
            gl2lds16(ag[i], &lsA[0][(wid * 32 + i * 8) * 64]);
        #pragma unroll
        for (int i = 0; i < 2; i++)
            gl2lds16(bg[i], &lsB[0][(wid * 16 + i * 8) * 64]);
        #pragma unroll
        for (int i = 0; i < 4; i++)
            gl2lds16(ag[i] + 64, &lsA[1][(wid * 32 + i * 8) * 64]);
        #pragma unroll
        for (int i = 0; i < 2; i++)
            gl2lds16(bg[i] + 64, &lsB[1][(wid * 16 + i * 8) * 64]);

        #pragma unroll
        for (int it = 0; it < 8; it++) {
            // tile it landed when <= 6 (the next tile's loads) outstanding
            if (it < 7) asm volatile("s_waitcnt vmcnt(6)" ::: "memory");
            else        asm volatile("s_waitcnt vmcnt(0)" ::: "memory");
            __builtin_amdgcn_s_barrier();
            __builtin_amdgcn_sched_barrier(0);
            const _Float16* la = lsA[it & 1];
            const _Float16* lb = lsB[it & 1];
            __builtin_amdgcn_s_setprio(1);
            #pragma unroll
            for (int kk = 0; kk < 64; kk += 32) {
                const int kc = (kk >> 3) + quad;
                half8 af[4], bf[4];
                #pragma unroll
                for (int mf = 0; mf < 4; mf++) {
                    int ar = wm + mf * 16 + l15;
                    int sw = ((kc ^ (ar & 7)) << 3);
                    af[mf] = *(const half8*)&la[ar * 64 + sw];
                }
                #pragma unroll
                for (int g = 0; g < 4; g++) {
                    int br = g * 32 + hgrp + l15;
                    int sw = ((kc ^ (br & 7)) << 3);
                    bf[g] = *(const half8*)&lb[br * 64 + sw];
                }
                #pragma unroll
                for (int mf = 0; mf < 4; mf++)
                    #pragma unroll
                    for (int g = 0; g < 4; g++)
                        acc[mf][g] = __builtin_amdgcn_mfma_f32_16x16x32_f16(
                            af[mf], bf[g], acc[mf][g], 0, 0, 0);
            }
            __builtin_amdgcn_s_setprio(0);
            if (it < 6) {
                __builtin_amdgcn_sched_barrier(0);
                __builtin_amdgcn_s_barrier();     // all waves done reading buf
                #pragma unroll
                for (int i = 0; i < 4; i++)
                    gl2lds16(ag[i] + (it + 2) * 64, &lsA[it & 1][(wid * 32 + i * 8) * 64]);
                #pragma unroll
                for (int i = 0; i < 2; i++)
                    gl2lds16(bg[i] + (it + 2) * 64, &lsB[it & 1][(wid * 16 + i * 8) * 64]);
            }
        }
    }

    // fused cell epilogue: acc[mf][gate][r] — all 4 gates per (row,hcol)
    const int hcol = c0 + hgrp + l15;
    #pragma unroll
    for (int mf = 0; mf < 4; mf++) {
        #pragma unroll
        for (int r = 0; r < 4; r++) {
            int row = m0 + wm + mf * 16 + quad * 4 + r;
            int tok = is_enc ? seq_s[row * SSRC + t]
                             : (t == 0 ? 1 : seq_s[row * STGT + t - 1]);  // SOS=1
            const fx4 xp = *(const fx4*)&proj[((size_t)tok * HD + hcol) << 2];
            float gi = acc[mf][0][r] + xp[0];
            float gf = acc[mf][1][r] + xp[1];
            float gg = acc[mf][2][r] + xp[2];
            float go = acc[mf][3][r] + xp[3];
            float ii = sigf(gi), ff = sigf(gf), oo = sigf(go);
            float g2 = tanhfast(gg);
            size_t off = (size_t)row * HD + hcol;
            float cold = c_state[off];
            float c2 = ff * cold + ii * g2;
            float h2 = oo * tanhfast(c2);
            bool cwrite = true;
            if (is_enc) {
                int len = lens_s[row];
                if (t >= len) {               // pack_padded semantics
                    c2 = cold;
                    cwrite = false;           // value identical -> skip write
                    h2 = (float)h_r[off];     // exact fp16 carry
                }
                if (t + 1 == len)             // row's final h (bitwise = R10)
                    hfinal[off] = (_Float16)h2;
            }
            if (cwrite) c_state[off] = c2;
            h_w[off] = (_Float16)h2;
        }
    }
}

// Batched outproj: 512 blocks = (16 t) x (32 m-tiles), each 128x128x512.
// 2 blocks/CU exact fill. Rows in sorted space; scatter via perm.
__global__ __launch_bounds__(256, 2) void outproj_batch(
    const _Float16* __restrict__ h_slots, int t0,
    const _Float16* __restrict__ Wo, const float* __restrict__ bout,
    const int* __restrict__ perm,
    float* __restrict__ out)
{
    __shared__ __align__(16) _Float16 lsA[128 * 64];
    __shared__ __align__(16) _Float16 lsB[128 * 64];

    const int tid = threadIdx.x;
    const int lane = tid & 63;
    const int wid  = tid >> 6;
    const int srow = lane >> 3;
    const int skc  = (((lane & 7) ^ srow)) << 3;
    const int wm    = (wid >> 1) * 64;
    const int wncol = wid & 1;
    const int quad  = lane >> 4;
    const int l15   = lane & 15;
    const int bsw   = (l15 & 7);

    const int t  = t0 + ((int)blockIdx.x >> 5);        // 16 t per launch
    const int m0 = ((int)blockIdx.x & 31) * 128;
    const _Float16* h_r = h_slots + (size_t)(t & 15) * NBHD;   // ring-16

    const _Float16 *ag[4], *bg[4];
    #pragma unroll
    for (int i = 0; i < 4; i++) {
        int lr = wid * 32 + i * 8 + srow;
        ag[i] = h_r + (size_t)(m0 + lr) * HD + skc;
        bg[i] = Wo + (size_t)lr * HD + skc;   // Wout row = v
    }

    fx4 acc[4][4];
    #pragma unroll
    for (int i = 0; i < 4; i++)
        #pragma unroll
        for (int jj = 0; jj < 4; jj++)
            acc[i][jj] = fx4{0.f, 0.f, 0.f, 0.f};

    for (int k0 = 0; k0 < HD; k0 += 64) {
        __syncthreads();
        #pragma unroll
        for (int i = 0; i < 4; i++) {
            int lb = (wid * 32 + i * 8) * 64;
            gl2lds16(ag[i] + k0, &lsA[lb]);
            gl2lds16(bg[i] + k0, &lsB[lb]);
        }
        __syncthreads();
        #pragma unroll
        for (int kk = 0; kk < 64; kk += 32) {
            const int kc = (kk >> 3) + quad;
            const int sw = ((kc ^ bsw) << 3);
            half8 af[4], bf[4];
            #pragma unroll
            for (int mt = 0; mt < 4; mt++)
                af[mt] = *(const half8*)&lsA[(wm + mt * 16 + l15) * 64 + sw];
            #pragma unroll
            for (int nt = 0; nt < 4; nt++)
                bf[nt] = *(const half8*)&lsB[(wncol * 64 + nt * 16 + l15) * 64 + sw];
            #pragma unroll
            for (int mt = 0; mt < 4; mt++)
                #pragma unroll
                for (int nt = 0; nt < 4; nt++)
                    acc[mt][nt] = __builtin_amdgcn_mfma_f32_16x16x32_f16(af[mt], bf[nt], acc[mt][nt], 0, 0, 0);
        }
    }

    #pragma unroll
    for (int mt = 0; mt < 4; mt++)
        #pragma unroll
        for (int nt = 0; nt < 4; nt++) {
            int v = wncol * 64 + nt * 16 + l15;
            float bo = bout[v];
            #pragma unroll
            for (int r = 0; r < 4; r++) {
                int row = m0 + wm + mt * 16 + quad * 4 + r;   // sorted space
                int orow = perm[row];
                out[((size_t)orow * STGT + t) * NVTGT + v] = acc[mt][nt][r] + bo;
            }
        }
}

extern "C" void kernel_launch(void* const* d_in, const int* in_sizes, int n_in,
                              void* d_out, int out_size, void* d_ws, size_t ws_size,
                              hipStream_t stream) {
    (void)in_sizes; (void)n_in; (void)out_size; (void)ws_size;
    const int* src_seq = (const int*)d_in[0];
    const int* src_len = (const int*)d_in[1];
    const int* tgt_seq = (const int*)d_in[2];
    const float* emb_src = (const float*)d_in[3];
    const float* eWih = (const float*)d_in[4];
    const float* eWhh = (const float*)d_in[5];
    const float* ebih = (const float*)d_in[6];
    const float* ebhh = (const float*)d_in[7];
    const float* emb_tgt = (const float*)d_in[8];
    const float* dWih = (const float*)d_in[9];
    const float* dWhh = (const float*)d_in[10];
    const float* dbih = (const float*)d_in[11];
    const float* dbhh = (const float*)d_in[12];
    const float* Wout = (const float*)d_in[13];
    const float* bout = (const float*)d_in[14];
    float* out = (float*)d_out;

    char* ws = (char*)d_ws;
    size_t off = 0;
    auto carve = [&](size_t bytes) { void* p = ws + off; off += (bytes + 255) & ~(size_t)255; return p; };
    float* proj_src = (float*)carve((size_t)NVSRC * G4 * 4);
    float* proj_tgt = (float*)carve((size_t)NVTGT * G4 * 4);
    float* c_state  = (float*)carve(NBHD * 4);
    _Float16* slots = (_Float16*)carve((size_t)18 * NBHD * 2);   // 72 MB
    _Float16* eW_h  = (_Float16*)carve((size_t)G4 * HD * 2);
    _Float16* dW_h  = (_Float16*)carve((size_t)G4 * HD * 2);
    _Float16* Wo_h  = (_Float16*)carve((size_t)NVTGT * HD * 2);
    _Float16* hfinal = (_Float16*)carve(NBHD * 2);               // 4 MB
    int* perm   = (int*)carve((size_t)NB * 4);
    int* lens_s = (int*)carve((size_t)NB * 4);
    int* maxlen = (int*)carve(32 * 4);
    int* src_s  = (int*)carve((size_t)NB * SSRC * 4);
    int* tgt_s  = (int*)carve((size_t)NB * STGT * 4);
    // WT buffers alias decoder slot 0 (first written at decoder step 0,
    // long after tables are built). 1 MB each, slot is 4 MB.
    float* WT_e = (float*)(slots);
    float* WT_d = (float*)((char*)slots + (size_t)ED * G4 * 4);
    auto slot = [&](int i) { return slots + (size_t)i * NBHD; };

    hipMemsetAsync(c_state, 0, NBHD * 4, stream);

    sort_rows<<<dim3(1), dim3(256), 0, stream>>>(src_len, perm, lens_s, maxlen);
    gather_seq2<<<dim3(2 * NB * SSRC / 256), dim3(256), 0, stream>>>(
        src_seq, tgt_seq, perm, src_s, tgt_s);

    {
        int n1 = G4 * HD, n2 = G4 * HD, n3 = NVTGT * HD;
        int nb = (n1 + n2 + n3 + 255) / 256;
        convert_all<<<dim3(nb), dim3(256), 0, stream>>>(
            eWhh, n1, eW_h, dWhh, n2, dW_h, Wout, n3, Wo_h);
    }
    transpose2_f32<<<dim3(512), dim3(256), 0, stream>>>(eWih, WT_e, dWih, WT_d);
    build_tables2<<<dim3((NVSRC / 8) * 8 + (NVTGT / 8) * 8), dim3(256), 0, stream>>>(
        emb_src, WT_e, ebih, ebhh, proj_src,
        emb_tgt, WT_d, dbih, dbhh, proj_tgt);

    // encoder: slots 16/17 alternate; s=0 skips GEMM (h==0; frozen path
    // never taken at t=0 since len>=1). Finals -> hfinal/c_state.
    for (int s = 0; s < 32; s++) {
        lstm_step<<<dim3(256), dim3(512), 0, stream>>>(
            slot(16 + (s & 1)), slot(16 + ((s + 1) & 1)), c_state,
            proj_src, src_s, lens_s, maxlen, eW_h, hfinal, s, 1, (s == 0));
    }
    // decoder: 16-slot ring (slot = t mod 16); t=0 reads hfinal.
    // outproj after t=15 and t=31 (512 blocks, 16 timesteps each).
    for (int t = 0; t < 32; t++) {
        const _Float16* hr = (t == 0) ? hfinal : slot((t - 1) & 15);
        lstm_step<<<dim3(256), dim3(512), 0, stream>>>(
            hr, slot(t & 15), c_state,
            proj_tgt, tgt_s, lens_s, maxlen, dW_h, hfinal, t, 0, 0);
        if ((t & 15) == 15) {
            outproj_batch<<<dim3(512), dim3(256), 0, stream>>>(
                slots, t - 15, Wo_h, bout, perm, out);
        }
    }
}

// Round 11
// 1330.099 us; speedup vs baseline: 1.3525x; 1.3525x over previous
//
#include <hip/hip_runtime.h>
#include <hip/hip_bf16.h>
#include <hip/hip_fp16.h>
#include <stdint.h>

// Seq2Seq LSTM: B=4096, H=512, E=128, 32 enc + 32 dec steps, V_tgt=128.
// Round 21: REVERT to R18 (proven best, 1369.7us) + redundant-write skip.
// Ledger: R13/R19 null; R11/12/14 manual-sync much worse; R16 LDS-free
// much worse; R20 BM=256 @1blk/CU much worse (lost co-resident-block TLP).
// Tiling optimum at 2 blk/CU: min 4*C_T+2*M_T s.t. M_T*C_T=512 -> (32,16)
// = exactly R18. New (bit-exact): encoder h_w store skipped for t > len —
// after the single copy at t==len, BOTH alternating slots hold the final h
// (induction), so later stores re-write identical bits. absmax unchanged.

#define NB     4096
#define SSRC   32
#define STGT   32
#define NVSRC  96
#define NVTGT  128
#define ED     128
#define HD     512
#define G4     2048   // 4*HD
#define NBHD   ((size_t)NB * HD)

typedef __attribute__((ext_vector_type(8))) _Float16 half8;
typedef __attribute__((ext_vector_type(4))) float fx4;

#define AS_G __attribute__((address_space(1)))
#define AS_L __attribute__((address_space(3)))

__device__ __forceinline__ void gl2lds16(const void* g, void* l) {
    // async global->LDS DMA, 16B/lane; LDS dest = wave-uniform base + lane*16
    __builtin_amdgcn_global_load_lds((const AS_G uint32_t*)g, (AS_L uint32_t*)l, 16, 0, 0);
}

__device__ __forceinline__ float sigf(float x) { return 1.0f / (1.0f + __expf(-x)); }
__device__ __forceinline__ float tanhfast(float x) { return 1.0f - 2.0f / (__expf(2.0f * x) + 1.0f); }

// One launch converts eWhh, dWhh, Wout to fp16 (three segments).
__global__ __launch_bounds__(256) void convert_all(
    const float* __restrict__ s1, int n1, _Float16* __restrict__ d1,
    const float* __restrict__ s2, int n2, _Float16* __restrict__ d2,
    const float* __restrict__ s3, int n3, _Float16* __restrict__ d3)
{
    int i = (int)blockIdx.x * 256 + threadIdx.x;
    if (i < n1) { d1[i] = (_Float16)s1[i]; return; }
    i -= n1;
    if (i < n2) { d2[i] = (_Float16)s2[i]; return; }
    i -= n2;
    if (i < n3) d3[i] = (_Float16)s3[i];
}

// Both Wih transposes (eWih, dWih) in one launch. R=G4, C=ED.
__global__ __launch_bounds__(256) void transpose2_f32(
    const float* __restrict__ inA, float* __restrict__ outTA,
    const float* __restrict__ inB, float* __restrict__ outTB)
{
    __shared__ float ls[32][33];
    int bid = (int)blockIdx.x;
    const float* in; float* outT;
    if (bid < 256) { in = inA; outT = outTA; }
    else           { in = inB; outT = outTB; bid -= 256; }
    const int rtiles = G4 / 32;                  // 64
    const int bx = bid % rtiles;                 // r-tile
    const int by = bid / rtiles;                 // c-tile
    const int tx = threadIdx.x & 31, ty = threadIdx.x >> 5;   // ty 0..7
    #pragma unroll
    for (int i = 0; i < 4; i++) {
        int rr = ty + i * 8;
        ls[rr][tx] = in[(size_t)(bx * 32 + rr) * ED + by * 32 + tx];
    }
    __syncthreads();
    #pragma unroll
    for (int i = 0; i < 4; i++) {
        int rr = ty + i * 8;
        outT[(size_t)(by * 32 + rr) * G4 + bx * 32 + tx] = ls[tx][rr];
    }
}

// proj[v][hcol][gate] = emb[v,:]·Wih[g,:] + bih[g] + bhh[g]  (gate-contig).
// Both vocab tables in one launch: blocks [0,96) = src, [96,224) = tgt.
__global__ __launch_bounds__(256) void build_tables2(
    const float* __restrict__ embS, const float* __restrict__ WTS,
    const float* __restrict__ bihS, const float* __restrict__ bhhS,
    float* __restrict__ projS,
    const float* __restrict__ embT, const float* __restrict__ WTT,
    const float* __restrict__ bihT, const float* __restrict__ bhhT,
    float* __restrict__ projT)
{
    __shared__ float embL[8][ED];
    int bid = (int)blockIdx.x;
    const float *emb, *WT, *bih, *bhh; float* proj;
    if (bid < (NVSRC / 8) * 8) { emb = embS; WT = WTS; bih = bihS; bhh = bhhS; proj = projS; }
    else { bid -= (NVSRC / 8) * 8; emb = embT; WT = WTT; bih = bihT; bhh = bhhT; proj = projT; }
    const int gc = bid & 7;
    const int vc = bid >> 3;
    const int g  = gc * 256 + threadIdx.x;
    for (int i = threadIdx.x; i < 8 * ED; i += 256)
        embL[i >> 7][i & (ED - 1)] = emb[(size_t)(vc * 8 + (i >> 7)) * ED + (i & (ED - 1))];
    __syncthreads();
    float acc[8] = {0, 0, 0, 0, 0, 0, 0, 0};
    for (int e = 0; e < ED; e++) {
        float w = WT[(size_t)e * G4 + g];
        #pragma unroll
        for (int v = 0; v < 8; v++) acc[v] += embL[v][e] * w;
    }
    float bb = bih[g] + bhh[g];
    const int gate = g >> 9, hcol = g & (HD - 1);
    #pragma unroll
    for (int v = 0; v < 8; v++)
        proj[(((size_t)(vc * 8 + v) * HD + hcol) << 2) + gate] = acc[v] + bb;
}

// Counting sort of rows by src length (keys 1..32). Single block.
// maxlen per 128-row tile (32 tiles) to match BM=128 lstm_step.
__global__ __launch_bounds__(256) void sort_rows(
    const int* __restrict__ lens, int* __restrict__ perm,
    int* __restrict__ lens_s, int* __restrict__ maxlen)
{
    __shared__ int hist[33];
    __shared__ int base[33];
    const int tid = threadIdx.x;
    if (tid < 33) hist[tid] = 0;
    __syncthreads();
    for (int i = tid; i < NB; i += 256) atomicAdd(&hist[lens[i]], 1);
    __syncthreads();
    if (tid == 0) {
        int s = 0;
        for (int l = 1; l <= 32; l++) { base[l] = s; s += hist[l]; }
    }
    __syncthreads();
    for (int i = tid; i < NB; i += 256) {
        int l = lens[i];
        int pos = atomicAdd(&base[l], 1);
        perm[pos] = i;
        lens_s[pos] = l;
    }
    __syncthreads();
    if (tid < 32) maxlen[tid] = lens_s[tid * 128 + 127];
}

// Gathers both src and tgt sequences through perm in one launch.
__global__ __launch_bounds__(256) void gather_seq2(
    const int* __restrict__ src, const int* __restrict__ tgt,
    const int* __restrict__ perm,
    int* __restrict__ src_s, int* __restrict__ tgt_s)
{
    int i = (int)blockIdx.x * 256 + threadIdx.x;   // over 2*NB*32
    int half = i >> 17;                            // NB*32 = 131072 = 1<<17
    int k = i & ((NB * 32) - 1);
    int row = k >> 5, t = k & 31;
    if (half == 0) src_s[k] = src[perm[row] * 32 + t];
    else           tgt_s[k] = tgt[perm[row] * 32 + t];
}

// Gate GEMM, 128m x 128n (4 gates x 32 hcols) per block + fused epilogue.
// 512 blocks x 512 threads (8 waves), 2 blocks/CU = 16 waves/CU.
// Wave = 32m x 64n: 2 m-frags x 4 n-frags, n-frag == gate at hcol group
// hgrp=(wid>>2)*16 -> each lane owns all 4 gates per (row,hcol).
__global__ __launch_bounds__(512, 4) void lstm_step(
    const _Float16* __restrict__ h_r, _Float16* __restrict__ h_w,
    float* __restrict__ c_state,
    const float* __restrict__ proj,      // [tok][hcol][4]
    const int* __restrict__ seq_s, const int* __restrict__ lens_s,
    const int* __restrict__ maxlen,
    const _Float16* __restrict__ W,
    _Float16* __restrict__ hfinal,
    int t, int is_enc, int skip_gemm)
{
    __shared__ __align__(16) _Float16 lsA[128 * 64];   // 16 KB
    __shared__ __align__(16) _Float16 lsB[128 * 64];   // 16 KB

    const int tid = threadIdx.x;
    const int lane = tid & 63;
    const int wid  = tid >> 6;                     // 0..7
    const int srow = lane >> 3;                    // staging row-in-group
    const int skc  = (((lane & 7) ^ srow)) << 3;   // XOR-swizzled k-chunk
    const int wm   = (wid & 3) * 32;               // wave m-offset (0..96)
    const int hgrp = (wid >> 2) * 16;              // hcol 16-group in c-tile
    const int quad = lane >> 4;
    const int l15  = lane & 15;

    // XCD swizzle: per-XCD ws = 16 m-tiles + 4 c-tiles
    const int x = (int)blockIdx.x & 7, j = (int)blockIdx.x >> 3;
    const int mt = (x & 1) * 16 + (j & 15);            // m-tile (sorted space)
    const int m0 = mt * 128;
    const int c0 = ((x >> 1) * 4 + (j >> 4)) * 32;     // hcol tile (16 total)

    // whole tile frozen: every row already wrote hfinal; c_state holds finals
    if (is_enc && t >= maxlen[mt]) return;

    const _Float16 *ag[2], *bg[2];
    #pragma unroll
    for (int i = 0; i < 2; i++) {
        int lr = wid * 16 + i * 8 + srow;              // local row 0..127
        ag[i] = h_r + (size_t)(m0 + lr) * HD + skc;
        // B row lr -> (gate = lr>>5, hc = lr&31)
        int wr = (lr >> 5) * HD + c0 + (lr & 31);
        bg[i] = W + (size_t)wr * HD + skc;
    }

    fx4 acc[2][4];
    #pragma unroll
    for (int i = 0; i < 2; i++)
        #pragma unroll
        for (int jj = 0; jj < 4; jj++)
            acc[i][jj] = fx4{0.f, 0.f, 0.f, 0.f};

    if (!skip_gemm) {
        for (int k0 = 0; k0 < HD; k0 += 64) {
            __syncthreads();
            #pragma unroll
            for (int i = 0; i < 2; i++) {
                gl2lds16(ag[i] + k0, &lsA[(wid * 16 + i * 8) * 64]);
                gl2lds16(bg[i] + k0, &lsB[(wid * 16 + i * 8) * 64]);
            }
            __syncthreads();
            #pragma unroll
            for (int kk = 0; kk < 64; kk += 32) {
                const int kc = (kk >> 3) + quad;
                half8 af[2], bf[4];
                #pragma unroll
                for (int mf = 0; mf < 2; mf++) {
                    int ar = wm + mf * 16 + l15;
                    int sw = ((kc ^ (ar & 7)) << 3);
                    af[mf] = *(const half8*)&lsA[ar * 64 + sw];
                }
                #pragma unroll
                for (int g = 0; g < 4; g++) {
                    int br = g * 32 + hgrp + l15;
                    int sw = ((kc ^ (br & 7)) << 3);
                    bf[g] = *(const half8*)&lsB[br * 64 + sw];
                }
                #pragma unroll
                for (int mf = 0; mf < 2; mf++)
                    #pragma unroll
                    for (int g = 0; g < 4; g++)
                        acc[mf][g] = __builtin_amdgcn_mfma_f32_16x16x32_f16(af[mf], bf[g], acc[mf][g], 0, 0, 0);
            }
        }
    }

    // fused cell epilogue: acc[mf][gate][r] — all 4 gates per (row,hcol)
    const int hcol = c0 + hgrp + l15;
    #pragma unroll
    for (int mf = 0; mf < 2; mf++) {
        #pragma unroll
        for (int r = 0; r < 4; r++) {
            int row = m0 + wm + mf * 16 + quad * 4 + r;
            int tok = is_enc ? seq_s[row * SSRC + t]
                             : (t == 0 ? 1 : seq_s[row * STGT + t - 1]);  // SOS=1
            const fx4 xp = *(const fx4*)&proj[((size_t)tok * HD + hcol) << 2];
            float gi = acc[mf][0][r] + xp[0];
            float gf = acc[mf][1][r] + xp[1];
            float gg = acc[mf][2][r] + xp[2];
            float go = acc[mf][3][r] + xp[3];
            float ii = sigf(gi), ff = sigf(gf), oo = sigf(go);
            float g2 = tanhfast(gg);
            size_t off = (size_t)row * HD + hcol;
            float cold = c_state[off];
            float c2 = ff * cold + ii * g2;
            float h2 = oo * tanhfast(c2);
            bool cwrite = true, hwrite = true;
            if (is_enc) {
                int len = lens_s[row];
                if (t >= len) {               // pack_padded semantics
                    c2 = cold;
                    cwrite = false;           // identical value -> skip write
                    if (t == len) h2 = (float)h_r[off];  // one exact fp16 copy
                    else hwrite = false;      // both slots already final (ind.)
                }
                if (t + 1 == len)             // row's final h (bitwise = R10)
                    hfinal[off] = (_Float16)h2;
            }
            if (cwrite) c_state[off] = c2;
            if (hwrite) h_w[off] = (_Float16)h2;
        }
    }
}

// Batched outproj: 512 blocks = (16 t) x (32 m-tiles), each 128x128x512.
// 2 blocks/CU exact fill. Rows in sorted space; scatter via perm.
__global__ __launch_bounds__(256, 2) void outproj_batch(
    const _Float16* __restrict__ h_slots, int t0,
    const _Float16* __restrict__ Wo, const float* __restrict__ bout,
    const int* __restrict__ perm,
    float* __restrict__ out)
{
    __shared__ __align__(16) _Float16 lsA[128 * 64];
    __shared__ __align__(16) _Float16 lsB[128 * 64];

    const int tid = threadIdx.x;
    const int lane = tid & 63;
    const int wid  = tid >> 6;
    const int srow = lane >> 3;
    const int skc  = (((lane & 7) ^ srow)) << 3;
    const int wm    = (wid >> 1) * 64;
    const int wncol = wid & 1;
    const int quad  = lane >> 4;
    const int l15   = lane & 15;
    const int bsw   = (l15 & 7);

    const int t  = t0 + ((int)blockIdx.x >> 5);        // 16 t per launch
    const int m0 = ((int)blockIdx.x & 31) * 128;
    const _Float16* h_r = h_slots + (size_t)(t & 15) * NBHD;   // ring-16

    const _Float16 *ag[4], *bg[4];
    #pragma unroll
    for (int i = 0; i < 4; i++) {
        int lr = wid * 32 + i * 8 + srow;
        ag[i] = h_r + (size_t)(m0 + lr) * HD + skc;
        bg[i] = Wo + (size_t)lr * HD + skc;   // Wout row = v
    }

    fx4 acc[4][4];
    #pragma unroll
    for (int i = 0; i < 4; i++)
        #pragma unroll
        for (int jj = 0; jj < 4; jj++)
            acc[i][jj] = fx4{0.f, 0.f, 0.f, 0.f};

    for (int k0 = 0; k0 < HD; k0 += 64) {
        __syncthreads();
        #pragma unroll
        for (int i = 0; i < 4; i++) {
            int lb = (wid * 32 + i * 8) * 64;
            gl2lds16(ag[i] + k0, &lsA[lb]);
            gl2lds16(bg[i] + k0, &lsB[lb]);
        }
        __syncthreads();
        #pragma unroll
        for (int kk = 0; kk < 64; kk += 32) {
            const int kc = (kk >> 3) + quad;
            const int sw = ((kc ^ bsw) << 3);
            half8 af[4], bf[4];
            #pragma unroll
            for (int mt = 0; mt < 4; mt++)
                af[mt] = *(const half8*)&lsA[(wm + mt * 16 + l15) * 64 + sw];
            #pragma unroll
            for (int nt = 0; nt < 4; nt++)
                bf[nt] = *(const half8*)&lsB[(wncol * 64 + nt * 16 + l15) * 64 + sw];
            #pragma unroll
            for (int mt = 0; mt < 4; mt++)
                #pragma unroll
                for (int nt = 0; nt < 4; nt++)
                    acc[mt][nt] = __builtin_amdgcn_mfma_f32_16x16x32_f16(af[mt], bf[nt], acc[mt][nt], 0, 0, 0);
        }
    }

    #pragma unroll
    for (int mt = 0; mt < 4; mt++)
        #pragma unroll
        for (int nt = 0; nt < 4; nt++) {
            int v = wncol * 64 + nt * 16 + l15;
            float bo = bout[v];
            #pragma unroll
            for (int r = 0; r < 4; r++) {
                int row = m0 + wm + mt * 16 + quad * 4 + r;   // sorted space
                int orow = perm[row];
                out[((size_t)orow * STGT + t) * NVTGT + v] = acc[mt][nt][r] + bo;
            }
        }
}

extern "C" void kernel_launch(void* const* d_in, const int* in_sizes, int n_in,
                              void* d_out, int out_size, void* d_ws, size_t ws_size,
                              hipStream_t stream) {
    (void)in_sizes; (void)n_in; (void)out_size; (void)ws_size;
    const int* src_seq = (const int*)d_in[0];
    const int* src_len = (const int*)d_in[1];
    const int* tgt_seq = (const int*)d_in[2];
    const float* emb_src = (const float*)d_in[3];
    const float* eWih = (const float*)d_in[4];
    const float* eWhh = (const float*)d_in[5];
    const float* ebih = (const float*)d_in[6];
    const float* ebhh = (const float*)d_in[7];
    const float* emb_tgt = (const float*)d_in[8];
    const float* dWih = (const float*)d_in[9];
    const float* dWhh = (const float*)d_in[10];
    const float* dbih = (const float*)d_in[11];
    const float* dbhh = (const float*)d_in[12];
    const float* Wout = (const float*)d_in[13];
    const float* bout = (const float*)d_in[14];
    float* out = (float*)d_out;

    char* ws = (char*)d_ws;
    size_t off = 0;
    auto carve = [&](size_t bytes) { void* p = ws + off; off += (bytes + 255) & ~(size_t)255; return p; };
    float* proj_src = (float*)carve((size_t)NVSRC * G4 * 4);
    float* proj_tgt = (float*)carve((size_t)NVTGT * G4 * 4);
    float* c_state  = (float*)carve(NBHD * 4);
    _Float16* slots = (_Float16*)carve((size_t)18 * NBHD * 2);   // 72 MB
    _Float16* eW_h  = (_Float16*)carve((size_t)G4 * HD * 2);
    _Float16* dW_h  = (_Float16*)carve((size_t)G4 * HD * 2);
    _Float16* Wo_h  = (_Float16*)carve((size_t)NVTGT * HD * 2);
    _Float16* hfinal = (_Float16*)carve(NBHD * 2);               // 4 MB
    int* perm   = (int*)carve((size_t)NB * 4);
    int* lens_s = (int*)carve((size_t)NB * 4);
    int* maxlen = (int*)carve(32 * 4);
    int* src_s  = (int*)carve((size_t)NB * SSRC * 4);
    int* tgt_s  = (int*)carve((size_t)NB * STGT * 4);
    // WT buffers alias decoder slot 0 (first written at decoder step 0,
    // long after tables are built). 1 MB each, slot is 4 MB.
    float* WT_e = (float*)(slots);
    float* WT_d = (float*)((char*)slots + (size_t)ED * G4 * 4);
    auto slot = [&](int i) { return slots + (size_t)i * NBHD; };

    hipMemsetAsync(c_state, 0, NBHD * 4, stream);

    sort_rows<<<dim3(1), dim3(256), 0, stream>>>(src_len, perm, lens_s, maxlen);
    gather_seq2<<<dim3(2 * NB * SSRC / 256), dim3(256), 0, stream>>>(
        src_seq, tgt_seq, perm, src_s, tgt_s);

    {
        int n1 = G4 * HD, n2 = G4 * HD, n3 = NVTGT * HD;
        int nb = (n1 + n2 + n3 + 255) / 256;
        convert_all<<<dim3(nb), dim3(256), 0, stream>>>(
            eWhh, n1, eW_h, dWhh, n2, dW_h, Wout, n3, Wo_h);
    }
    transpose2_f32<<<dim3(512), dim3(256), 0, stream>>>(eWih, WT_e, dWih, WT_d);
    build_tables2<<<dim3((NVSRC / 8) * 8 + (NVTGT / 8) * 8), dim3(256), 0, stream>>>(
        emb_src, WT_e, ebih, ebhh, proj_src,
        emb_tgt, WT_d, dbih, dbhh, proj_tgt);

    // encoder: slots 16/17 alternate; s=0 skips GEMM (h==0; frozen path
    // never taken at t=0 since len>=1). Finals -> hfinal/c_state.
    for (int s = 0; s < 32; s++) {
        lstm_step<<<dim3(512), dim3(512), 0, stream>>>(
            slot(16 + (s & 1)), slot(16 + ((s + 1) & 1)), c_state,
            proj_src, src_s, lens_s, maxlen, eW_h, hfinal, s, 1, (s == 0));
    }
    // decoder: 16-slot ring (slot = t mod 16); t=0 reads hfinal.
    // outproj after t=15 and t=31 (512 blocks, 16 timesteps each).
    for (int t = 0; t < 32; t++) {
        const _Float16* hr = (t == 0) ? hfinal : slot((t - 1) & 15);
        lstm_step<<<dim3(512), dim3(512), 0, stream>>>(
            hr, slot(t & 15), c_state,
            proj_tgt, tgt_s, lens_s, maxlen, dW_h, hfinal, t, 0, 0);
        if ((t & 15) == 15) {
            outproj_batch<<<dim3(512), dim3(256), 0, stream>>>(
                slots, t - 15, Wo_h, bout, perm, out);
        }
    }
}